// Round 7
// baseline (409.888 us; speedup 1.0000x reference)
//
#include <hip/hip_runtime.h>
#include <math.h>

// RowLSTM: x(16,64,64,64) fp32, Wi(512,64,1,3), bi(512), Wh(512,128), bh(512)
// out: (16,128,64,64) fp32
//
// Gate-row permutation: slot(gate,d) = (d>>4)*64 + gate*16 + (d&15).
// K0 k_pack: Wi -> bf16 hi/lo, FRAG-MAJOR: WipF[(((kw*2+kf)*8+wv)*4+mf)*64+lane][8]
// K1 k_conv: MFMA conv (3 shifted K=64 GEMMs); xT[w][c] bf16 hi/lo in LDS,
//            stride 136 shorts, contiguous u16x8 staging writes (conflict-free).
//            i2h[b][h][wq][col][slot] = conv + bi + bh (fp32)
// K2 k_lstm: 32 WGs = (b, wpair); each WG runs TWO 16-col tiles (shared Wh frags)
//            -> two independent dep chains interleave, hiding latency.
//
// ws: [0, 33554432) fp32 i2h; then WipF hi (98304 u16), lo (98304 u16)

#define BB 16
#define CC 64
#define HH 64
#define WW 64
#define HID 128
#define GG 512
#define KW 3

typedef __attribute__((ext_vector_type(8))) short short8;
typedef __attribute__((ext_vector_type(4))) float f32x4;
typedef __attribute__((ext_vector_type(4))) unsigned short u16x4;
typedef __attribute__((ext_vector_type(8))) unsigned short u16x8;

__device__ inline unsigned short f32_to_bf16_rne(float f) {
    unsigned int u = __float_as_uint(f);
    unsigned int r = (u + 0x7fffu + ((u >> 16) & 1u)) >> 16;
    return (unsigned short)r;
}
__device__ inline float bf16_to_f32(unsigned short s) {
    return __uint_as_float(((unsigned int)s) << 16);
}

// ---------------- K0: pack Wi -> bf16 hi/lo, frag-major ----------------
__global__ __launch_bounds__(256) void k_pack(const float* __restrict__ Wi,
                                              unsigned short* __restrict__ Whi,
                                              unsigned short* __restrict__ Wlo) {
    int n = blockIdx.x * 256 + threadIdx.x;  // 98304 total
    int j = n & 7;
    int lane = (n >> 3) & 63;
    int mf = (n >> 9) & 3;
    int wv = (n >> 11) & 7;
    int kf = (n >> 14) & 1;
    int kw = n >> 15;
    int lr = lane & 15;
    int lq = lane >> 4;
    int gd = mf * 128 + wv * 16 + lr;    // gate*128 + d
    int c = kf * 32 + lq * 8 + j;
    float v = Wi[(size_t)gd * (CC * KW) + c * 3 + kw];
    unsigned short hb = f32_to_bf16_rne(v);
    Whi[n] = hb;
    Wlo[n] = f32_to_bf16_rne(v - bf16_to_f32(hb));
}

// ---------------- K1: conv via MFMA ----------------
// 1024 WGs = (b,h); 512 thr = 8 waves. Wave wv -> slots [64wv,64wv+64), all 64 cols.
__global__ __launch_bounds__(512, 2) void k_conv(const float* __restrict__ x,
                                                 const unsigned short* __restrict__ Whi,
                                                 const unsigned short* __restrict__ Wlo,
                                                 const float* __restrict__ bi,
                                                 const float* __restrict__ bh,
                                                 float* __restrict__ i2h) {
    __shared__ __align__(16) unsigned short xhiT[66 * 136];  // xT[wi][c] = x[c][wi-1]
    __shared__ __align__(16) unsigned short xloT[66 * 136];  // rows 0,65 zero pad

    const int b = blockIdx.x >> 6;
    const int h = blockIdx.x & 63;
    const int t = threadIdx.x;
    const int lane = t & 63;
    const int wv = t >> 6;
    const int lr = lane & 15;
    const int lq = lane >> 4;

    // stage: thread = (w = t&63, c-octet = t>>6). 8 coalesced b32 loads,
    // one contiguous u16x8 write per array (272B row stride -> 2-way free).
    {
        const int w = t & 63;
        const int c8 = t >> 6;
        float vv[8];
        #pragma unroll
        for (int j = 0; j < 8; ++j)
            vv[j] = x[(((size_t)b * CC + c8 * 8 + j) * HH + h) * WW + w];
        u16x8 hv, lv;
        #pragma unroll
        for (int j = 0; j < 8; ++j) {
            unsigned short hb = f32_to_bf16_rne(vv[j]);
            hv[j] = hb;
            lv[j] = f32_to_bf16_rne(vv[j] - bf16_to_f32(hb));
        }
        *(u16x8*)&xhiT[(w + 1) * 136 + c8 * 8] = hv;
        *(u16x8*)&xloT[(w + 1) * 136 + c8 * 8] = lv;
        if (t < 136) {
            xhiT[t] = 0; xloT[t] = 0;
            xhiT[65 * 136 + t] = 0; xloT[65 * 136 + t] = 0;
        }
    }

    // acc init = bias
    f32x4 acc[4][4];  // [mf][nf]
    #pragma unroll
    for (int mf = 0; mf < 4; ++mf) {
        #pragma unroll
        for (int r = 0; r < 4; ++r) {
            const int gd = mf * 128 + wv * 16 + lq * 4 + r;
            const float bias = bi[gd] + bh[gd];
            #pragma unroll
            for (int nf = 0; nf < 4; ++nf) acc[mf][nf][r] = bias;
        }
    }
    __syncthreads();

    #pragma unroll
    for (int kw = 0; kw < 3; ++kw) {
        #pragma unroll
        for (int kf = 0; kf < 2; ++kf) {
            short8 Ah[4], Al[4];
            #pragma unroll
            for (int mf = 0; mf < 4; ++mf) {
                const size_t abase =
                    ((size_t)((((kw * 2 + kf) * 8 + wv) * 4 + mf) * 64) + lane) * 8;
                Ah[mf] = *(const short8*)&Whi[abase];   // coalesced 1KB
                Al[mf] = *(const short8*)&Wlo[abase];
            }
            short8 Bh[4], Bl[4];
            #pragma unroll
            for (int nf = 0; nf < 4; ++nf) {
                const int baddr = (nf * 16 + lr + kw) * 136 + kf * 32 + lq * 8;
                Bh[nf] = *(const short8*)&xhiT[baddr];
                Bl[nf] = *(const short8*)&xloT[baddr];
            }
            #pragma unroll
            for (int mf = 0; mf < 4; ++mf) {
                #pragma unroll
                for (int nf = 0; nf < 4; ++nf) {
                    acc[mf][nf] = __builtin_amdgcn_mfma_f32_16x16x32_bf16(Al[mf], Bh[nf], acc[mf][nf], 0, 0, 0);
                    acc[mf][nf] = __builtin_amdgcn_mfma_f32_16x16x32_bf16(Ah[mf], Bl[nf], acc[mf][nf], 0, 0, 0);
                    acc[mf][nf] = __builtin_amdgcn_mfma_f32_16x16x32_bf16(Ah[mf], Bh[nf], acc[mf][nf], 0, 0, 0);
                }
            }
        }
    }

    // store i2h[b][h][nf][col=lr][slot]
    const size_t obase0 = (((size_t)b * HH + h) * 4);
    #pragma unroll
    for (int nf = 0; nf < 4; ++nf) {
        #pragma unroll
        for (int mf = 0; mf < 4; ++mf) {
            const size_t idx = ((obase0 + nf) * 16 + lr) * GG + wv * 64 + mf * 16 + lq * 4;
            *(f32x4*)&i2h[idx] = acc[mf][nf];
        }
    }
}

// ---------------- K2: recurrent scan, 2 tiles/WG ----------------
// 32 WGs = (b, wpair); tiles T=0,1 -> wq = 2*wpair+T. 8 waves, M=512 each tile.
#define IDXH(T, buf, col, d) (((((T)*2 + (buf)) * 16 + (col)) * 136) + (d))

__global__ __launch_bounds__(512, 2) void k_lstm(const float* __restrict__ i2h,
                                                 const float* __restrict__ Wh,
                                                 float* __restrict__ out) {
    __shared__ __align__(16) unsigned short hsh[2 * 2 * 16 * 136];  // [tile][buf][col][d] hi
    __shared__ __align__(16) unsigned short hsl[2 * 2 * 16 * 136];  // lo

    const int b = blockIdx.x >> 1;
    const int wp = blockIdx.x & 1;
    const int t = threadIdx.x;
    const int lane = t & 63;
    const int wv = t >> 6;
    const int lr = lane & 15;
    const int lq = lane >> 4;

    // A fragments: Wh row gd = mf*128 + wv*16 + lr, bf16 hi/lo (shared by both tiles)
    short8 ahi[4][4], alo[4][4];
    #pragma unroll
    for (int mf = 0; mf < 4; ++mf) {
        const int gd = mf * 128 + wv * 16 + lr;
        #pragma unroll
        for (int kf = 0; kf < 4; ++kf) {
            const float* src = &Wh[(size_t)gd * HID + kf * 32 + lq * 8];
            const f32x4 v0 = *(const f32x4*)src;
            const f32x4 v1 = *(const f32x4*)(src + 4);
            short8 h8, l8;
            #pragma unroll
            for (int j = 0; j < 4; ++j) {
                unsigned short hb = f32_to_bf16_rne(v0[j]);
                h8[j] = (short)hb;
                l8[j] = (short)f32_to_bf16_rne(v0[j] - bf16_to_f32(hb));
                unsigned short hb2 = f32_to_bf16_rne(v1[j]);
                h8[4 + j] = (short)hb2;
                l8[4 + j] = (short)f32_to_bf16_rne(v1[j] - bf16_to_f32(hb2));
            }
            ahi[mf][kf] = h8;
            alo[mf][kf] = l8;
        }
    }

    // zero h buf 0 of both tiles
    for (int i = t; i < 2176; i += 512) {
        hsh[i] = 0; hsh[2 * 2176 + i] = 0;
        hsl[i] = 0; hsl[2 * 2176 + i] = 0;
    }

    float cellA[4] = {0.f, 0.f, 0.f, 0.f};
    float cellB[4] = {0.f, 0.f, 0.f, 0.f};

    const float* ibA =
        &i2h[((((size_t)b * HH) * 4 + (2 * wp + 0)) * 16 + lr) * GG + wv * 64 + lq * 4];
    const float* ibB =
        &i2h[((((size_t)b * HH) * 4 + (2 * wp + 1)) * 16 + lr) * GG + wv * 64 + lq * 4];
    const size_t rowstride = (size_t)4 * 16 * GG;

    f32x4 gA[4], gB[4];
    #pragma unroll
    for (int mf = 0; mf < 4; ++mf) {
        gA[mf] = *(const f32x4*)(ibA + mf * 16);
        gB[mf] = *(const f32x4*)(ibB + mf * 16);
    }
    __syncthreads();

    int cur = 0;
    for (int hr = 0; hr < HH; ++hr) {
        f32x4 accA[4], accB[4];
        #pragma unroll
        for (int mf = 0; mf < 4; ++mf) { accA[mf] = gA[mf]; accB[mf] = gB[mf]; }

        // prefetch next row's i2h (consumed next window)
        const int hn = (hr < HH - 1) ? hr + 1 : hr;
        #pragma unroll
        for (int mf = 0; mf < 4; ++mf) {
            gA[mf] = *(const f32x4*)(ibA + (size_t)hn * rowstride + mf * 16);
            gB[mf] = *(const f32x4*)(ibB + (size_t)hn * rowstride + mf * 16);
        }

        // gates += Wh * h, 3-term bf16 split, A/B tiles interleaved (8 indep chains)
        #pragma unroll
        for (int kf = 0; kf < 4; ++kf) {
            const int ba = kf * 32 + lq * 8;
            const short8 bhA = *(const short8*)&hsh[IDXH(0, cur, lr, ba)];
            const short8 blA = *(const short8*)&hsl[IDXH(0, cur, lr, ba)];
            const short8 bhB = *(const short8*)&hsh[IDXH(1, cur, lr, ba)];
            const short8 blB = *(const short8*)&hsl[IDXH(1, cur, lr, ba)];
            #pragma unroll
            for (int mf = 0; mf < 4; ++mf)
                accA[mf] = __builtin_amdgcn_mfma_f32_16x16x32_bf16(alo[mf][kf], bhA, accA[mf], 0, 0, 0);
            #pragma unroll
            for (int mf = 0; mf < 4; ++mf)
                accB[mf] = __builtin_amdgcn_mfma_f32_16x16x32_bf16(alo[mf][kf], bhB, accB[mf], 0, 0, 0);
            #pragma unroll
            for (int mf = 0; mf < 4; ++mf)
                accA[mf] = __builtin_amdgcn_mfma_f32_16x16x32_bf16(ahi[mf][kf], blA, accA[mf], 0, 0, 0);
            #pragma unroll
            for (int mf = 0; mf < 4; ++mf)
                accB[mf] = __builtin_amdgcn_mfma_f32_16x16x32_bf16(ahi[mf][kf], blB, accB[mf], 0, 0, 0);
            #pragma unroll
            for (int mf = 0; mf < 4; ++mf)
                accA[mf] = __builtin_amdgcn_mfma_f32_16x16x32_bf16(ahi[mf][kf], bhA, accA[mf], 0, 0, 0);
            #pragma unroll
            for (int mf = 0; mf < 4; ++mf)
                accB[mf] = __builtin_amdgcn_mfma_f32_16x16x32_bf16(ahi[mf][kf], bhB, accB[mf], 0, 0, 0);
        }

        // merged nonlinearity, both tiles (8 independent trans chains)
        const int nxt = cur ^ 1;
        u16x4 hbA, lbA, hbB, lbB;
        #pragma unroll
        for (int r = 0; r < 4; ++r) {
            const int d = wv * 16 + lq * 4 + r;
            {
                const float si = 1.f / (1.f + __expf(-accA[0][r]));
                const float sf = 1.f / (1.f + __expf(-accA[1][r]));
                const float so = 1.f / (1.f + __expf(-accA[2][r]));
                const float tg = 1.f - 2.f / (__expf(2.f * accA[3][r]) + 1.f);
                cellA[r] = sf * cellA[r] + si * tg;
                const float th = 1.f - 2.f / (__expf(2.f * cellA[r]) + 1.f);
                const float hv = so * th;
                out[(((size_t)b * HID + d) * HH + hr) * WW + (2 * wp + 0) * 16 + lr] = hv;
                const unsigned short hb = f32_to_bf16_rne(hv);
                hbA[r] = hb;
                lbA[r] = f32_to_bf16_rne(hv - bf16_to_f32(hb));
            }
            {
                const float si = 1.f / (1.f + __expf(-accB[0][r]));
                const float sf = 1.f / (1.f + __expf(-accB[1][r]));
                const float so = 1.f / (1.f + __expf(-accB[2][r]));
                const float tg = 1.f - 2.f / (__expf(2.f * accB[3][r]) + 1.f);
                cellB[r] = sf * cellB[r] + si * tg;
                const float th = 1.f - 2.f / (__expf(2.f * cellB[r]) + 1.f);
                const float hv = so * th;
                out[(((size_t)b * HID + d) * HH + hr) * WW + (2 * wp + 1) * 16 + lr] = hv;
                const unsigned short hb = f32_to_bf16_rne(hv);
                hbB[r] = hb;
                lbB[r] = f32_to_bf16_rne(hv - bf16_to_f32(hb));
            }
        }
        *(u16x4*)&hsh[IDXH(0, nxt, lr, wv * 16 + lq * 4)] = hbA;
        *(u16x4*)&hsl[IDXH(0, nxt, lr, wv * 16 + lq * 4)] = lbA;
        *(u16x4*)&hsh[IDXH(1, nxt, lr, wv * 16 + lq * 4)] = hbB;
        *(u16x4*)&hsl[IDXH(1, nxt, lr, wv * 16 + lq * 4)] = lbB;

        __syncthreads();
        cur = nxt;
    }
}

extern "C" void kernel_launch(void* const* d_in, const int* in_sizes, int n_in,
                              void* d_out, int out_size, void* d_ws, size_t ws_size,
                              hipStream_t stream) {
    const float* x  = (const float*)d_in[0];
    const float* Wi = (const float*)d_in[1];
    const float* bi = (const float*)d_in[2];
    const float* Wh = (const float*)d_in[3];
    const float* bh = (const float*)d_in[4];
    float* out = (float*)d_out;
    float* ws  = (float*)d_ws;

    float* i2h = ws;  // 33554432 floats
    unsigned short* Whi = (unsigned short*)(ws + 33554432);  // 98304 u16
    unsigned short* Wlo = Whi + 98304;

    hipLaunchKernelGGL(k_pack, dim3(384), dim3(256), 0, stream, Wi, Whi, Wlo);
    hipLaunchKernelGGL(k_conv, dim3(BB * HH), dim3(512), 0, stream, x, Whi, Wlo, bi, bh, i2h);
    hipLaunchKernelGGL(k_lstm, dim3(BB * 2), dim3(512), 0, stream, i2h, Wh, out);
}

// Round 8
// 257.881 us; speedup vs baseline: 1.5894x; 1.5894x over previous
//
#include <hip/hip_runtime.h>
#include <math.h>

// RowLSTM: x(16,64,64,64) fp32, Wi(512,64,1,3), bi(512), Wh(512,128), bh(512)
// out: (16,128,64,64) fp32
//
// Gate-row permutation: slot(gate,d) = (d>>4)*64 + gate*16 + (d&15).
// K0 k_pack: Wi -> bf16 hi/lo, FRAG-MAJOR: WipF[(((kw*2+kf)*8+wv)*4+mf)*64+lane][8]
// K1 k_conv: MFMA conv (3 shifted K=64 GEMMs); xT[w][c] bf16 hi/lo in LDS.
//            i2h[b][h][wq][col][slot] = conv + bi + bh (fp32)
// K2 k_lstm: 64 WGs = (b,wq); 8 waves; 3-term bf16-split MFMA; in-reg gates.
//
// launch_bounds(512, 1): VGPR budget 256 (8 waves/WG = 2/SIMD resident).
// At (512,2) the 128-cap spilled the 128-VGPR weight array -> scratch traffic
// every step (R6/R7 regression root cause).
//
// ws: [0, 33554432) fp32 i2h; then WipF hi (98304 u16), lo (98304 u16)

#define BB 16
#define CC 64
#define HH 64
#define WW 64
#define HID 128
#define GG 512
#define KW 3

typedef __attribute__((ext_vector_type(8))) short short8;
typedef __attribute__((ext_vector_type(4))) float f32x4;
typedef __attribute__((ext_vector_type(4))) unsigned short u16x4;
typedef __attribute__((ext_vector_type(8))) unsigned short u16x8;

__device__ inline unsigned short f32_to_bf16_rne(float f) {
    unsigned int u = __float_as_uint(f);
    unsigned int r = (u + 0x7fffu + ((u >> 16) & 1u)) >> 16;
    return (unsigned short)r;
}
__device__ inline float bf16_to_f32(unsigned short s) {
    return __uint_as_float(((unsigned int)s) << 16);
}

// ---------------- K0: pack Wi -> bf16 hi/lo, frag-major ----------------
__global__ __launch_bounds__(256) void k_pack(const float* __restrict__ Wi,
                                              unsigned short* __restrict__ Whi,
                                              unsigned short* __restrict__ Wlo) {
    int n = blockIdx.x * 256 + threadIdx.x;  // 98304 total
    int j = n & 7;
    int lane = (n >> 3) & 63;
    int mf = (n >> 9) & 3;
    int wv = (n >> 11) & 7;
    int kf = (n >> 14) & 1;
    int kw = n >> 15;
    int lr = lane & 15;
    int lq = lane >> 4;
    int gd = mf * 128 + wv * 16 + lr;    // gate*128 + d
    int c = kf * 32 + lq * 8 + j;
    float v = Wi[(size_t)gd * (CC * KW) + c * 3 + kw];
    unsigned short hb = f32_to_bf16_rne(v);
    Whi[n] = hb;
    Wlo[n] = f32_to_bf16_rne(v - bf16_to_f32(hb));
}

// ---------------- K1: conv via MFMA ----------------
// 1024 WGs = (b,h); 512 thr = 8 waves. Wave wv -> slots [64wv,64wv+64), all 64 cols.
__global__ __launch_bounds__(512, 1) void k_conv(const float* __restrict__ x,
                                                 const unsigned short* __restrict__ Whi,
                                                 const unsigned short* __restrict__ Wlo,
                                                 const float* __restrict__ bi,
                                                 const float* __restrict__ bh,
                                                 float* __restrict__ i2h) {
    __shared__ __align__(16) unsigned short xhiT[66 * 136];  // xT[wi][c] = x[c][wi-1]
    __shared__ __align__(16) unsigned short xloT[66 * 136];  // rows 0,65 zero pad

    const int b = blockIdx.x >> 6;
    const int h = blockIdx.x & 63;
    const int t = threadIdx.x;
    const int lane = t & 63;
    const int wv = t >> 6;
    const int lr = lane & 15;
    const int lq = lane >> 4;

    // stage: thread = (w = t&63, c-octet = t>>6). 8 coalesced b32 loads,
    // one contiguous u16x8 write per array.
    {
        const int w = t & 63;
        const int c8 = t >> 6;
        float vv[8];
        #pragma unroll
        for (int j = 0; j < 8; ++j)
            vv[j] = x[(((size_t)b * CC + c8 * 8 + j) * HH + h) * WW + w];
        u16x8 hv, lv;
        #pragma unroll
        for (int j = 0; j < 8; ++j) {
            unsigned short hb = f32_to_bf16_rne(vv[j]);
            hv[j] = hb;
            lv[j] = f32_to_bf16_rne(vv[j] - bf16_to_f32(hb));
        }
        *(u16x8*)&xhiT[(w + 1) * 136 + c8 * 8] = hv;
        *(u16x8*)&xloT[(w + 1) * 136 + c8 * 8] = lv;
        if (t < 136) {
            xhiT[t] = 0; xloT[t] = 0;
            xhiT[65 * 136 + t] = 0; xloT[65 * 136 + t] = 0;
        }
    }

    // acc init = bias
    f32x4 acc[4][4];  // [mf][nf]
    #pragma unroll
    for (int mf = 0; mf < 4; ++mf) {
        #pragma unroll
        for (int r = 0; r < 4; ++r) {
            const int gd = mf * 128 + wv * 16 + lq * 4 + r;
            const float bias = bi[gd] + bh[gd];
            #pragma unroll
            for (int nf = 0; nf < 4; ++nf) acc[mf][nf][r] = bias;
        }
    }
    __syncthreads();

    #pragma unroll
    for (int kw = 0; kw < 3; ++kw) {
        #pragma unroll
        for (int kf = 0; kf < 2; ++kf) {
            short8 Ah[4], Al[4];
            #pragma unroll
            for (int mf = 0; mf < 4; ++mf) {
                const size_t abase =
                    ((size_t)((((kw * 2 + kf) * 8 + wv) * 4 + mf) * 64) + lane) * 8;
                Ah[mf] = *(const short8*)&Whi[abase];   // coalesced 1KB
                Al[mf] = *(const short8*)&Wlo[abase];
            }
            short8 Bh[4], Bl[4];
            #pragma unroll
            for (int nf = 0; nf < 4; ++nf) {
                const int baddr = (nf * 16 + lr + kw) * 136 + kf * 32 + lq * 8;
                Bh[nf] = *(const short8*)&xhiT[baddr];
                Bl[nf] = *(const short8*)&xloT[baddr];
            }
            #pragma unroll
            for (int mf = 0; mf < 4; ++mf) {
                #pragma unroll
                for (int nf = 0; nf < 4; ++nf) {
                    acc[mf][nf] = __builtin_amdgcn_mfma_f32_16x16x32_bf16(Al[mf], Bh[nf], acc[mf][nf], 0, 0, 0);
                    acc[mf][nf] = __builtin_amdgcn_mfma_f32_16x16x32_bf16(Ah[mf], Bl[nf], acc[mf][nf], 0, 0, 0);
                    acc[mf][nf] = __builtin_amdgcn_mfma_f32_16x16x32_bf16(Ah[mf], Bh[nf], acc[mf][nf], 0, 0, 0);
                }
            }
        }
    }

    // store i2h[b][h][nf][col=lr][slot]
    const size_t obase0 = (((size_t)b * HH + h) * 4);
    #pragma unroll
    for (int nf = 0; nf < 4; ++nf) {
        #pragma unroll
        for (int mf = 0; mf < 4; ++mf) {
            const size_t idx = ((obase0 + nf) * 16 + lr) * GG + wv * 64 + mf * 16 + lq * 4;
            *(f32x4*)&i2h[idx] = acc[mf][nf];
        }
    }
}

// ---------------- K2: recurrent scan, in-register gates ----------------
// 64 WGs = (b,wq); 8 waves; wave wv -> d in [16wv,16wv+16), cols wq*16..+15.
__global__ __launch_bounds__(512, 1) void k_lstm(const float* __restrict__ i2h,
                                                 const float* __restrict__ Wh,
                                                 float* __restrict__ out) {
    __shared__ __align__(16) unsigned short hTh[2 * 16 * 136];  // [buf][col][d]
    __shared__ __align__(16) unsigned short hTl[2 * 16 * 136];

    const int b = blockIdx.x >> 2;
    const int wq = blockIdx.x & 3;
    const int t = threadIdx.x;
    const int lane = t & 63;
    const int wv = t >> 6;
    const int lr = lane & 15;
    const int lq = lane >> 4;

    // A fragments: Wh row gd = mf*128 + wv*16 + lr (gate-permuted), bf16 hi/lo.
    // 128 VGPRs -- requires the 256 budget from launch_bounds(512,1).
    short8 ahi[4][4], alo[4][4];
    #pragma unroll
    for (int mf = 0; mf < 4; ++mf) {
        const int gd = mf * 128 + wv * 16 + lr;
        #pragma unroll
        for (int kf = 0; kf < 4; ++kf) {
            const float* src = &Wh[(size_t)gd * HID + kf * 32 + lq * 8];
            const f32x4 v0 = *(const f32x4*)src;
            const f32x4 v1 = *(const f32x4*)(src + 4);
            short8 h8, l8;
            #pragma unroll
            for (int j = 0; j < 4; ++j) {
                unsigned short hb = f32_to_bf16_rne(v0[j]);
                h8[j] = (short)hb;
                l8[j] = (short)f32_to_bf16_rne(v0[j] - bf16_to_f32(hb));
                unsigned short hb2 = f32_to_bf16_rne(v1[j]);
                h8[4 + j] = (short)hb2;
                l8[4 + j] = (short)f32_to_bf16_rne(v1[j] - bf16_to_f32(hb2));
            }
            ahi[mf][kf] = h8;
            alo[mf][kf] = l8;
        }
    }

    for (int i = t; i < 2176; i += 512) { hTh[i] = 0; hTl[i] = 0; }  // buf 0

    float cell[4] = {0.f, 0.f, 0.f, 0.f};

    // incremental pointers
    const size_t rowstride = (size_t)4 * 16 * GG;
    const float* ip =
        &i2h[((((size_t)b * HH) * 4 + wq) * 16 + lr) * GG + wv * 64 + lq * 4];
    float* op = &out[(((size_t)b * HID + (wv * 16 + lq * 4)) * HH) * WW + wq * 16 + lr];

    f32x4 gbuf[4];
    #pragma unroll
    for (int mf = 0; mf < 4; ++mf) gbuf[mf] = *(const f32x4*)(ip + mf * 16);

    __syncthreads();

    int cur = 0;
    for (int hr = 0; hr < HH; ++hr) {
        f32x4 acc[4];
        #pragma unroll
        for (int mf = 0; mf < 4; ++mf) acc[mf] = gbuf[mf];

        // prefetch next row's i2h (consumed next iteration)
        if (hr < HH - 1) ip += rowstride;
        #pragma unroll
        for (int mf = 0; mf < 4; ++mf) gbuf[mf] = *(const f32x4*)(ip + mf * 16);

        // gates += Wh * h (3-term split); B from hT[cur]
        #pragma unroll
        for (int kf = 0; kf < 4; ++kf) {
            const int baddr = (cur * 16 + lr) * 136 + kf * 32 + lq * 8;
            const short8 bhf = *(const short8*)&hTh[baddr];
            const short8 blf = *(const short8*)&hTl[baddr];
            #pragma unroll
            for (int mf = 0; mf < 4; ++mf)
                acc[mf] = __builtin_amdgcn_mfma_f32_16x16x32_bf16(alo[mf][kf], bhf, acc[mf], 0, 0, 0);
            #pragma unroll
            for (int mf = 0; mf < 4; ++mf)
                acc[mf] = __builtin_amdgcn_mfma_f32_16x16x32_bf16(ahi[mf][kf], blf, acc[mf], 0, 0, 0);
            #pragma unroll
            for (int mf = 0; mf < 4; ++mf)
                acc[mf] = __builtin_amdgcn_mfma_f32_16x16x32_bf16(ahi[mf][kf], bhf, acc[mf], 0, 0, 0);
        }

        // in-register nonlinearity: lane owns (d = wv*16 + lq*4 + r, col = lr)
        const int nxt = cur ^ 1;
        u16x4 hb4, lb4;
        #pragma unroll
        for (int r = 0; r < 4; ++r) {
            const float si = 1.f / (1.f + __expf(-acc[0][r]));
            const float sf = 1.f / (1.f + __expf(-acc[1][r]));
            const float so = 1.f / (1.f + __expf(-acc[2][r]));
            const float tg = 1.f - 2.f / (__expf(2.f * acc[3][r]) + 1.f);
            cell[r] = sf * cell[r] + si * tg;
            const float th = 1.f - 2.f / (__expf(2.f * cell[r]) + 1.f);
            const float hv = so * th;
            op[(size_t)r * (HH * WW)] = hv;
            const unsigned short hb = f32_to_bf16_rne(hv);
            hb4[r] = hb;
            lb4[r] = f32_to_bf16_rne(hv - bf16_to_f32(hb));
        }
        op += WW;
        const int haddr = (nxt * 16 + lr) * 136 + wv * 16 + lq * 4;
        *(u16x4*)&hTh[haddr] = hb4;
        *(u16x4*)&hTl[haddr] = lb4;

        __syncthreads();
        cur = nxt;
    }
}

extern "C" void kernel_launch(void* const* d_in, const int* in_sizes, int n_in,
                              void* d_out, int out_size, void* d_ws, size_t ws_size,
                              hipStream_t stream) {
    const float* x  = (const float*)d_in[0];
    const float* Wi = (const float*)d_in[1];
    const float* bi = (const float*)d_in[2];
    const float* Wh = (const float*)d_in[3];
    const float* bh = (const float*)d_in[4];
    float* out = (float*)d_out;
    float* ws  = (float*)d_ws;

    float* i2h = ws;  // 33554432 floats
    unsigned short* Whi = (unsigned short*)(ws + 33554432);  // 98304 u16
    unsigned short* Wlo = Whi + 98304;

    hipLaunchKernelGGL(k_pack, dim3(384), dim3(256), 0, stream, Wi, Whi, Wlo);
    hipLaunchKernelGGL(k_conv, dim3(BB * HH), dim3(512), 0, stream, x, Whi, Wlo, bi, bh, i2h);
    hipLaunchKernelGGL(k_lstm, dim3(BB * 4), dim3(512), 0, stream, i2h, Wh, out);
}

// Round 9
// 255.505 us; speedup vs baseline: 1.6042x; 1.0093x over previous
//
#include <hip/hip_runtime.h>
#include <math.h>

// RowLSTM: x(16,64,64,64) fp32, Wi(512,64,1,3), bi(512), Wh(512,128), bh(512)
// out: (16,128,64,64) fp32
//
// Gate-row permutation: slot(gate,d) = (d>>4)*64 + gate*16 + (d&15).
// K0 k_pack: Wi -> bf16 hi/lo, frag-major
// K1 k_conv: MFMA conv (3 shifted K=64 GEMMs); i2h[b][h][wq][col][slot] (fp32)
// K2 k_lstm: 64 WGs = (b,wq); 8 waves; 3-term bf16-split MFMA; in-reg gates;
//            frag-major h in LDS (linear ds_read_b128, conflict-free);
//            raw s_barrier with lgkmcnt-only drain (i2h prefetch + out stores
//            stay in flight across the barrier -- kills the ~4500 cyc/step
//            vmcnt(0) drain the compiler emits for __syncthreads).
//
// ws: [0, 33554432) fp32 i2h; then WipF hi (98304 u16), lo (98304 u16)

#define BB 16
#define CC 64
#define HH 64
#define WW 64
#define HID 128
#define GG 512
#define KW 3

typedef __attribute__((ext_vector_type(8))) short short8;
typedef __attribute__((ext_vector_type(4))) float f32x4;
typedef __attribute__((ext_vector_type(4))) unsigned short u16x4;
typedef __attribute__((ext_vector_type(8))) unsigned short u16x8;

__device__ inline unsigned short f32_to_bf16_rne(float f) {
    unsigned int u = __float_as_uint(f);
    unsigned int r = (u + 0x7fffu + ((u >> 16) & 1u)) >> 16;
    return (unsigned short)r;
}
__device__ inline float bf16_to_f32(unsigned short s) {
    return __uint_as_float(((unsigned int)s) << 16);
}

// ---------------- K0: pack Wi -> bf16 hi/lo, frag-major ----------------
__global__ __launch_bounds__(256) void k_pack(const float* __restrict__ Wi,
                                              unsigned short* __restrict__ Whi,
                                              unsigned short* __restrict__ Wlo) {
    int n = blockIdx.x * 256 + threadIdx.x;  // 98304 total
    int j = n & 7;
    int lane = (n >> 3) & 63;
    int mf = (n >> 9) & 3;
    int wv = (n >> 11) & 7;
    int kf = (n >> 14) & 1;
    int kw = n >> 15;
    int lr = lane & 15;
    int lq = lane >> 4;
    int gd = mf * 128 + wv * 16 + lr;    // gate*128 + d
    int c = kf * 32 + lq * 8 + j;
    float v = Wi[(size_t)gd * (CC * KW) + c * 3 + kw];
    unsigned short hb = f32_to_bf16_rne(v);
    Whi[n] = hb;
    Wlo[n] = f32_to_bf16_rne(v - bf16_to_f32(hb));
}

// ---------------- K1: conv via MFMA ----------------
// 1024 WGs = (b,h); 512 thr = 8 waves. Wave wv -> slots [64wv,64wv+64), all 64 cols.
__global__ __launch_bounds__(512, 1) void k_conv(const float* __restrict__ x,
                                                 const unsigned short* __restrict__ Whi,
                                                 const unsigned short* __restrict__ Wlo,
                                                 const float* __restrict__ bi,
                                                 const float* __restrict__ bh,
                                                 float* __restrict__ i2h) {
    __shared__ __align__(16) unsigned short xhiT[66 * 136];  // xT[wi][c] = x[c][wi-1]
    __shared__ __align__(16) unsigned short xloT[66 * 136];  // rows 0,65 zero pad

    const int b = blockIdx.x >> 6;
    const int h = blockIdx.x & 63;
    const int t = threadIdx.x;
    const int lane = t & 63;
    const int wv = t >> 6;
    const int lr = lane & 15;
    const int lq = lane >> 4;

    // stage: thread = (w = t&63, c-octet = t>>6). 8 coalesced b32 loads,
    // one contiguous u16x8 write per array.
    {
        const int w = t & 63;
        const int c8 = t >> 6;
        float vv[8];
        #pragma unroll
        for (int j = 0; j < 8; ++j)
            vv[j] = x[(((size_t)b * CC + c8 * 8 + j) * HH + h) * WW + w];
        u16x8 hv, lv;
        #pragma unroll
        for (int j = 0; j < 8; ++j) {
            unsigned short hb = f32_to_bf16_rne(vv[j]);
            hv[j] = hb;
            lv[j] = f32_to_bf16_rne(vv[j] - bf16_to_f32(hb));
        }
        *(u16x8*)&xhiT[(w + 1) * 136 + c8 * 8] = hv;
        *(u16x8*)&xloT[(w + 1) * 136 + c8 * 8] = lv;
        if (t < 136) {
            xhiT[t] = 0; xloT[t] = 0;
            xhiT[65 * 136 + t] = 0; xloT[65 * 136 + t] = 0;
        }
    }

    // acc init = bias
    f32x4 acc[4][4];  // [mf][nf]
    #pragma unroll
    for (int mf = 0; mf < 4; ++mf) {
        #pragma unroll
        for (int r = 0; r < 4; ++r) {
            const int gd = mf * 128 + wv * 16 + lq * 4 + r;
            const float bias = bi[gd] + bh[gd];
            #pragma unroll
            for (int nf = 0; nf < 4; ++nf) acc[mf][nf][r] = bias;
        }
    }
    __syncthreads();

    #pragma unroll
    for (int kw = 0; kw < 3; ++kw) {
        #pragma unroll
        for (int kf = 0; kf < 2; ++kf) {
            short8 Ah[4], Al[4];
            #pragma unroll
            for (int mf = 0; mf < 4; ++mf) {
                const size_t abase =
                    ((size_t)((((kw * 2 + kf) * 8 + wv) * 4 + mf) * 64) + lane) * 8;
                Ah[mf] = *(const short8*)&Whi[abase];   // coalesced 1KB
                Al[mf] = *(const short8*)&Wlo[abase];
            }
            short8 Bh[4], Bl[4];
            #pragma unroll
            for (int nf = 0; nf < 4; ++nf) {
                const int baddr = (nf * 16 + lr + kw) * 136 + kf * 32 + lq * 8;
                Bh[nf] = *(const short8*)&xhiT[baddr];
                Bl[nf] = *(const short8*)&xloT[baddr];
            }
            #pragma unroll
            for (int mf = 0; mf < 4; ++mf) {
                #pragma unroll
                for (int nf = 0; nf < 4; ++nf) {
                    acc[mf][nf] = __builtin_amdgcn_mfma_f32_16x16x32_bf16(Al[mf], Bh[nf], acc[mf][nf], 0, 0, 0);
                    acc[mf][nf] = __builtin_amdgcn_mfma_f32_16x16x32_bf16(Ah[mf], Bl[nf], acc[mf][nf], 0, 0, 0);
                    acc[mf][nf] = __builtin_amdgcn_mfma_f32_16x16x32_bf16(Ah[mf], Bh[nf], acc[mf][nf], 0, 0, 0);
                }
            }
        }
    }

    // store i2h[b][h][nf][col=lr][slot]
    const size_t obase0 = (((size_t)b * HH + h) * 4);
    #pragma unroll
    for (int nf = 0; nf < 4; ++nf) {
        #pragma unroll
        for (int mf = 0; mf < 4; ++mf) {
            const size_t idx = ((obase0 + nf) * 16 + lr) * GG + wv * 64 + mf * 16 + lq * 4;
            *(f32x4*)&i2h[idx] = acc[mf][nf];
        }
    }
}

// ---------------- K2: recurrent scan, in-register gates ----------------
// 64 WGs = (b,wq); 8 waves; wave wv -> d in [16wv,16wv+16), cols wq*16..+15.
// h state frag-major in LDS: hF[buf][g][lane][8], g = kf (hi) / 4+kf (lo).
__global__ __launch_bounds__(512, 1) void k_lstm(const float* __restrict__ i2h,
                                                 const float* __restrict__ Wh,
                                                 float* __restrict__ out) {
    __shared__ __align__(16) unsigned short hF[2][8][64][8];  // 16 KB

    const int b = blockIdx.x >> 2;
    const int wq = blockIdx.x & 3;
    const int t = threadIdx.x;
    const int lane = t & 63;
    const int wv = t >> 6;
    const int lr = lane & 15;
    const int lq = lane >> 4;

    // A fragments: Wh row gd = mf*128 + wv*16 + lr (gate-permuted), bf16 hi/lo.
    short8 ahi[4][4], alo[4][4];
    #pragma unroll
    for (int mf = 0; mf < 4; ++mf) {
        const int gd = mf * 128 + wv * 16 + lr;
        #pragma unroll
        for (int kf = 0; kf < 4; ++kf) {
            const float* src = &Wh[(size_t)gd * HID + kf * 32 + lq * 8];
            const f32x4 v0 = *(const f32x4*)src;
            const f32x4 v1 = *(const f32x4*)(src + 4);
            short8 h8, l8;
            #pragma unroll
            for (int j = 0; j < 4; ++j) {
                unsigned short hb = f32_to_bf16_rne(v0[j]);
                h8[j] = (short)hb;
                l8[j] = (short)f32_to_bf16_rne(v0[j] - bf16_to_f32(hb));
                unsigned short hb2 = f32_to_bf16_rne(v1[j]);
                h8[4 + j] = (short)hb2;
                l8[4 + j] = (short)f32_to_bf16_rne(v1[j] - bf16_to_f32(hb2));
            }
            ahi[mf][kf] = h8;
            alo[mf][kf] = l8;
        }
    }

    // zero h buf 0 (8*64*8 = 4096 u16)
    *(u16x8*)&hF[0][0][0][0 + t * 8 - (t * 8 & 7)] = (u16x8)(0);  // avoid UB: plain index
    // (rewrite simply:)
    {
        u16x8 z = {0, 0, 0, 0, 0, 0, 0, 0};
        *(u16x8*)&(((unsigned short*)hF)[t * 8]) = z;
    }

    float cell[4] = {0.f, 0.f, 0.f, 0.f};

    // incremental pointers
    const size_t rowstride = (size_t)4 * 16 * GG;
    const float* ip =
        &i2h[((((size_t)b * HH) * 4 + wq) * 16 + lr) * GG + wv * 64 + lq * 4];
    float* op = &out[(((size_t)b * HID + (wv * 16 + lq * 4)) * HH) * WW + wq * 16 + lr];

    f32x4 gbuf[4];
    #pragma unroll
    for (int mf = 0; mf < 4; ++mf) gbuf[mf] = *(const f32x4*)(ip + mf * 16);

    // write-side destination (constant per thread)
    const int kf_d = wv >> 1;
    const int lane_dest = ((wv & 1) * 2 + (lq >> 1)) * 16 + lr;
    const int j0 = (lq & 1) * 4;

    __syncthreads();

    int cur = 0;
    for (int hr = 0; hr < HH; ++hr) {
        f32x4 acc[4];
        #pragma unroll
        for (int mf = 0; mf < 4; ++mf) acc[mf] = gbuf[mf];

        // prefetch next row's i2h (floats across the barrier; consumed next iter)
        if (hr < HH - 1) ip += rowstride;
        #pragma unroll
        for (int mf = 0; mf < 4; ++mf) gbuf[mf] = *(const f32x4*)(ip + mf * 16);

        // gates += Wh * h (3-term split); B = linear ds_read_b128 (conflict-free)
        const unsigned short* hbase = &hF[cur][0][lane][0];
        #pragma unroll
        for (int kf = 0; kf < 4; ++kf) {
            const short8 bhf = *(const short8*)(hbase + kf * 512);
            const short8 blf = *(const short8*)(hbase + (4 + kf) * 512);
            #pragma unroll
            for (int mf = 0; mf < 4; ++mf)
                acc[mf] = __builtin_amdgcn_mfma_f32_16x16x32_bf16(alo[mf][kf], bhf, acc[mf], 0, 0, 0);
            #pragma unroll
            for (int mf = 0; mf < 4; ++mf)
                acc[mf] = __builtin_amdgcn_mfma_f32_16x16x32_bf16(ahi[mf][kf], blf, acc[mf], 0, 0, 0);
            #pragma unroll
            for (int mf = 0; mf < 4; ++mf)
                acc[mf] = __builtin_amdgcn_mfma_f32_16x16x32_bf16(ahi[mf][kf], bhf, acc[mf], 0, 0, 0);
        }

        // in-register nonlinearity: lane owns (d = wv*16 + lq*4 + r, col = lr)
        const int nxt = cur ^ 1;
        u16x4 hb4, lb4;
        #pragma unroll
        for (int r = 0; r < 4; ++r) {
            const float si = 1.f / (1.f + __expf(-acc[0][r]));
            const float sf = 1.f / (1.f + __expf(-acc[1][r]));
            const float so = 1.f / (1.f + __expf(-acc[2][r]));
            const float tg = 1.f - 2.f / (__expf(2.f * acc[3][r]) + 1.f);
            cell[r] = sf * cell[r] + si * tg;
            const float th = 1.f - 2.f / (__expf(2.f * cell[r]) + 1.f);
            const float hv = so * th;
            op[(size_t)r * (HH * WW)] = hv;  // global store, floats across barrier
            const unsigned short hb = f32_to_bf16_rne(hv);
            hb4[r] = hb;
            lb4[r] = f32_to_bf16_rne(hv - bf16_to_f32(hb));
        }
        op += WW;

        // h-state write: value h[c = wv*16+lq*4+r][col = lr] -> frag slot
        *(u16x4*)&hF[nxt][kf_d][lane_dest][j0] = hb4;
        *(u16x4*)&hF[nxt][4 + kf_d][lane_dest][j0] = lb4;

        // drain LDS only; leave global loads/stores in flight (T4)
        asm volatile("s_waitcnt lgkmcnt(0)" ::: "memory");
        __builtin_amdgcn_s_barrier();
        __builtin_amdgcn_sched_barrier(0);

        cur = nxt;
    }
}

extern "C" void kernel_launch(void* const* d_in, const int* in_sizes, int n_in,
                              void* d_out, int out_size, void* d_ws, size_t ws_size,
                              hipStream_t stream) {
    const float* x  = (const float*)d_in[0];
    const float* Wi = (const float*)d_in[1];
    const float* bi = (const float*)d_in[2];
    const float* Wh = (const float*)d_in[3];
    const float* bh = (const float*)d_in[4];
    float* out = (float*)d_out;
    float* ws  = (float*)d_ws;

    float* i2h = ws;  // 33554432 floats
    unsigned short* Whi = (unsigned short*)(ws + 33554432);  // 98304 u16
    unsigned short* Wlo = Whi + 98304;

    hipLaunchKernelGGL(k_pack, dim3(384), dim3(256), 0, stream, Wi, Whi, Wlo);
    hipLaunchKernelGGL(k_conv, dim3(BB * HH), dim3(512), 0, stream, x, Whi, Wlo, bi, bh, i2h);
    hipLaunchKernelGGL(k_lstm, dim3(BB * 4), dim3(512), 0, stream, i2h, Wh, out);
}

// Round 11
// 209.736 us; speedup vs baseline: 1.9543x; 1.2182x over previous
//
#include <hip/hip_runtime.h>
#include <math.h>

// RowLSTM: x(16,64,64,64) fp32, Wi(512,64,1,3), bi(512), Wh(512,128), bh(512)
// out: (16,128,64,64) fp32
//
// Gate-row permutation: slot(gate,d) = (d>>4)*64 + gate*16 + (d&15).
// K0 k_pack: Wi -> bf16 hi/lo, frag-major
// K1 k_conv: MFMA conv (3 shifted K=64 GEMMs); i2h[b][h][wq][col][slot] (fp32)
// K2 k_lstm: 64 WGs = (b,wq); 8 waves; 3-term bf16-split MFMA; in-reg gates;
//            frag-major h in LDS (linear ds_read_b128, conflict-free);
//            raw s_barrier with lgkmcnt-only drain;
//            v_rcp_f32 nonlinearity (IEEE div sequence was ~440 VALU ops/thr/step
//            = the measured 60% active-CU VALUBusy -- R9 root cause).
//
// ws: [0, 33554432) fp32 i2h; then WipF hi (98304 u16), lo (98304 u16)

#define BB 16
#define CC 64
#define HH 64
#define WW 64
#define HID 128
#define GG 512
#define KW 3

typedef __attribute__((ext_vector_type(8))) short short8;
typedef __attribute__((ext_vector_type(4))) float f32x4;
typedef __attribute__((ext_vector_type(4))) unsigned short u16x4;
typedef __attribute__((ext_vector_type(8))) unsigned short u16x8;

__device__ inline unsigned short f32_to_bf16_rne(float f) {
    unsigned int u = __float_as_uint(f);
    unsigned int r = (u + 0x7fffu + ((u >> 16) & 1u)) >> 16;
    return (unsigned short)r;
}
__device__ inline float bf16_to_f32(unsigned short s) {
    return __uint_as_float(((unsigned int)s) << 16);
}
__device__ inline float fast_rcp(float x) { return __builtin_amdgcn_rcpf(x); }

// ---------------- K0: pack Wi -> bf16 hi/lo, frag-major ----------------
__global__ __launch_bounds__(256) void k_pack(const float* __restrict__ Wi,
                                              unsigned short* __restrict__ Whi,
                                              unsigned short* __restrict__ Wlo) {
    int n = blockIdx.x * 256 + threadIdx.x;  // 98304 total
    int j = n & 7;
    int lane = (n >> 3) & 63;
    int mf = (n >> 9) & 3;
    int wv = (n >> 11) & 7;
    int kf = (n >> 14) & 1;
    int kw = n >> 15;
    int lr = lane & 15;
    int lq = lane >> 4;
    int gd = mf * 128 + wv * 16 + lr;    // gate*128 + d
    int c = kf * 32 + lq * 8 + j;
    float v = Wi[(size_t)gd * (CC * KW) + c * 3 + kw];
    unsigned short hb = f32_to_bf16_rne(v);
    Whi[n] = hb;
    Wlo[n] = f32_to_bf16_rne(v - bf16_to_f32(hb));
}

// ---------------- K1: conv via MFMA ----------------
// 1024 WGs = (b,h); 512 thr = 8 waves. Wave wv -> slots [64wv,64wv+64), all 64 cols.
__global__ __launch_bounds__(512, 1) void k_conv(const float* __restrict__ x,
                                                 const unsigned short* __restrict__ Whi,
                                                 const unsigned short* __restrict__ Wlo,
                                                 const float* __restrict__ bi,
                                                 const float* __restrict__ bh,
                                                 float* __restrict__ i2h) {
    __shared__ __align__(16) unsigned short xhiT[66 * 136];  // xT[wi][c] = x[c][wi-1]
    __shared__ __align__(16) unsigned short xloT[66 * 136];  // rows 0,65 zero pad

    const int b = blockIdx.x >> 6;
    const int h = blockIdx.x & 63;
    const int t = threadIdx.x;
    const int lane = t & 63;
    const int wv = t >> 6;
    const int lr = lane & 15;
    const int lq = lane >> 4;

    // stage: thread = (w = t&63, c-octet = t>>6). 8 coalesced b32 loads,
    // one contiguous u16x8 write per array.
    {
        const int w = t & 63;
        const int c8 = t >> 6;
        float vv[8];
        #pragma unroll
        for (int j = 0; j < 8; ++j)
            vv[j] = x[(((size_t)b * CC + c8 * 8 + j) * HH + h) * WW + w];
        u16x8 hv, lv;
        #pragma unroll
        for (int j = 0; j < 8; ++j) {
            unsigned short hb = f32_to_bf16_rne(vv[j]);
            hv[j] = hb;
            lv[j] = f32_to_bf16_rne(vv[j] - bf16_to_f32(hb));
        }
        *(u16x8*)&xhiT[(w + 1) * 136 + c8 * 8] = hv;
        *(u16x8*)&xloT[(w + 1) * 136 + c8 * 8] = lv;
        if (t < 136) {
            xhiT[t] = 0; xloT[t] = 0;
            xhiT[65 * 136 + t] = 0; xloT[65 * 136 + t] = 0;
        }
    }

    // acc init = bias
    f32x4 acc[4][4];  // [mf][nf]
    #pragma unroll
    for (int mf = 0; mf < 4; ++mf) {
        #pragma unroll
        for (int r = 0; r < 4; ++r) {
            const int gd = mf * 128 + wv * 16 + lq * 4 + r;
            const float bias = bi[gd] + bh[gd];
            #pragma unroll
            for (int nf = 0; nf < 4; ++nf) acc[mf][nf][r] = bias;
        }
    }
    __syncthreads();

    #pragma unroll
    for (int kw = 0; kw < 3; ++kw) {
        #pragma unroll
        for (int kf = 0; kf < 2; ++kf) {
            short8 Ah[4], Al[4];
            #pragma unroll
            for (int mf = 0; mf < 4; ++mf) {
                const size_t abase =
                    ((size_t)((((kw * 2 + kf) * 8 + wv) * 4 + mf) * 64) + lane) * 8;
                Ah[mf] = *(const short8*)&Whi[abase];   // coalesced 1KB
                Al[mf] = *(const short8*)&Wlo[abase];
            }
            short8 Bh[4], Bl[4];
            #pragma unroll
            for (int nf = 0; nf < 4; ++nf) {
                const int baddr = (nf * 16 + lr + kw) * 136 + kf * 32 + lq * 8;
                Bh[nf] = *(const short8*)&xhiT[baddr];
                Bl[nf] = *(const short8*)&xloT[baddr];
            }
            #pragma unroll
            for (int mf = 0; mf < 4; ++mf) {
                #pragma unroll
                for (int nf = 0; nf < 4; ++nf) {
                    acc[mf][nf] = __builtin_amdgcn_mfma_f32_16x16x32_bf16(Al[mf], Bh[nf], acc[mf][nf], 0, 0, 0);
                    acc[mf][nf] = __builtin_amdgcn_mfma_f32_16x16x32_bf16(Ah[mf], Bl[nf], acc[mf][nf], 0, 0, 0);
                    acc[mf][nf] = __builtin_amdgcn_mfma_f32_16x16x32_bf16(Ah[mf], Bh[nf], acc[mf][nf], 0, 0, 0);
                }
            }
        }
    }

    // store i2h[b][h][nf][col=lr][slot]
    const size_t obase0 = (((size_t)b * HH + h) * 4);
    #pragma unroll
    for (int nf = 0; nf < 4; ++nf) {
        #pragma unroll
        for (int mf = 0; mf < 4; ++mf) {
            const size_t idx = ((obase0 + nf) * 16 + lr) * GG + wv * 64 + mf * 16 + lq * 4;
            *(f32x4*)&i2h[idx] = acc[mf][nf];
        }
    }
}

// ---------------- K2: recurrent scan, in-register gates ----------------
// 64 WGs = (b,wq); 8 waves; wave wv -> d in [16wv,16wv+16), cols wq*16..+15.
// h state frag-major in LDS: hF[buf][g][lane][8], g = kf (hi) / 4+kf (lo).
__global__ __launch_bounds__(512, 1) void k_lstm(const float* __restrict__ i2h,
                                                 const float* __restrict__ Wh,
                                                 float* __restrict__ out) {
    __shared__ __align__(16) unsigned short hF[2][8][64][8];  // 16 KB

    const int b = blockIdx.x >> 2;
    const int wq = blockIdx.x & 3;
    const int t = threadIdx.x;
    const int lane = t & 63;
    const int wv = t >> 6;
    const int lr = lane & 15;
    const int lq = lane >> 4;

    // A fragments: Wh row gd = mf*128 + wv*16 + lr (gate-permuted), bf16 hi/lo.
    short8 ahi[4][4], alo[4][4];
    #pragma unroll
    for (int mf = 0; mf < 4; ++mf) {
        const int gd = mf * 128 + wv * 16 + lr;
        #pragma unroll
        for (int kf = 0; kf < 4; ++kf) {
            const float* src = &Wh[(size_t)gd * HID + kf * 32 + lq * 8];
            const f32x4 v0 = *(const f32x4*)src;
            const f32x4 v1 = *(const f32x4*)(src + 4);
            short8 h8, l8;
            #pragma unroll
            for (int j = 0; j < 4; ++j) {
                unsigned short hb = f32_to_bf16_rne(v0[j]);
                h8[j] = (short)hb;
                l8[j] = (short)f32_to_bf16_rne(v0[j] - bf16_to_f32(hb));
                unsigned short hb2 = f32_to_bf16_rne(v1[j]);
                h8[4 + j] = (short)hb2;
                l8[4 + j] = (short)f32_to_bf16_rne(v1[j] - bf16_to_f32(hb2));
            }
            ahi[mf][kf] = h8;
            alo[mf][kf] = l8;
        }
    }

    // zero h buf 0 (8*64*8 = 4096 u16; 512 threads x u16x8)
    {
        u16x8 z = {0, 0, 0, 0, 0, 0, 0, 0};
        *(u16x8*)&(((unsigned short*)hF)[t * 8]) = z;
    }

    float cell[4] = {0.f, 0.f, 0.f, 0.f};

    // incremental pointers
    const size_t rowstride = (size_t)4 * 16 * GG;
    const float* ip =
        &i2h[((((size_t)b * HH) * 4 + wq) * 16 + lr) * GG + wv * 64 + lq * 4];
    float* op = &out[(((size_t)b * HID + (wv * 16 + lq * 4)) * HH) * WW + wq * 16 + lr];

    f32x4 gbuf[4];
    #pragma unroll
    for (int mf = 0; mf < 4; ++mf) gbuf[mf] = *(const f32x4*)(ip + mf * 16);

    // write-side destination (constant per thread)
    const int kf_d = wv >> 1;
    const int lane_dest = ((wv & 1) * 2 + (lq >> 1)) * 16 + lr;
    const int j0 = (lq & 1) * 4;

    __syncthreads();

    int cur = 0;
    for (int hr = 0; hr < HH; ++hr) {
        f32x4 acc[4];
        #pragma unroll
        for (int mf = 0; mf < 4; ++mf) acc[mf] = gbuf[mf];

        // prefetch next row's i2h (floats across the barrier; consumed next iter)
        if (hr < HH - 1) ip += rowstride;
        #pragma unroll
        for (int mf = 0; mf < 4; ++mf) gbuf[mf] = *(const f32x4*)(ip + mf * 16);

        // gates += Wh * h (3-term split); B = linear ds_read_b128 (conflict-free)
        const unsigned short* hbase = &hF[cur][0][lane][0];
        #pragma unroll
        for (int kf = 0; kf < 4; ++kf) {
            const short8 bhf = *(const short8*)(hbase + kf * 512);
            const short8 blf = *(const short8*)(hbase + (4 + kf) * 512);
            #pragma unroll
            for (int mf = 0; mf < 4; ++mf)
                acc[mf] = __builtin_amdgcn_mfma_f32_16x16x32_bf16(alo[mf][kf], bhf, acc[mf], 0, 0, 0);
            #pragma unroll
            for (int mf = 0; mf < 4; ++mf)
                acc[mf] = __builtin_amdgcn_mfma_f32_16x16x32_bf16(ahi[mf][kf], blf, acc[mf], 0, 0, 0);
            #pragma unroll
            for (int mf = 0; mf < 4; ++mf)
                acc[mf] = __builtin_amdgcn_mfma_f32_16x16x32_bf16(ahi[mf][kf], bhf, acc[mf], 0, 0, 0);
        }

        // in-register nonlinearity via v_rcp_f32 (1 ulp; bf16-split error dominates)
        const int nxt = cur ^ 1;
        u16x4 hb4, lb4;
        #pragma unroll
        for (int r = 0; r < 4; ++r) {
            const float si = fast_rcp(1.f + __expf(-acc[0][r]));
            const float sf = fast_rcp(1.f + __expf(-acc[1][r]));
            const float so = fast_rcp(1.f + __expf(-acc[2][r]));
            const float tg = 1.f - 2.f * fast_rcp(__expf(2.f * acc[3][r]) + 1.f);
            cell[r] = sf * cell[r] + si * tg;
            const float th = 1.f - 2.f * fast_rcp(__expf(2.f * cell[r]) + 1.f);
            const float hv = so * th;
            op[(size_t)r * (HH * WW)] = hv;  // global store, floats across barrier
            const unsigned short hb = f32_to_bf16_rne(hv);
            hb4[r] = hb;
            lb4[r] = f32_to_bf16_rne(hv - bf16_to_f32(hb));
        }
        op += WW;

        // h-state write: value h[c = wv*16+lq*4+r][col = lr] -> frag slot
        *(u16x4*)&hF[nxt][kf_d][lane_dest][j0] = hb4;
        *(u16x4*)&hF[nxt][4 + kf_d][lane_dest][j0] = lb4;

        // drain LDS only; leave global loads/stores in flight (T4)
        asm volatile("s_waitcnt lgkmcnt(0)" ::: "memory");
        __builtin_amdgcn_s_barrier();
        __builtin_amdgcn_sched_barrier(0);

        cur = nxt;
    }
}

extern "C" void kernel_launch(void* const* d_in, const int* in_sizes, int n_in,
                              void* d_out, int out_size, void* d_ws, size_t ws_size,
                              hipStream_t stream) {
    const float* x  = (const float*)d_in[0];
    const float* Wi = (const float*)d_in[1];
    const float* bi = (const float*)d_in[2];
    const float* Wh = (const float*)d_in[3];
    const float* bh = (const float*)d_in[4];
    float* out = (float*)d_out;
    float* ws  = (float*)d_ws;

    float* i2h = ws;  // 33554432 floats
    unsigned short* Whi = (unsigned short*)(ws + 33554432);  // 98304 u16
    unsigned short* Wlo = Whi + 98304;

    hipLaunchKernelGGL(k_pack, dim3(384), dim3(256), 0, stream, Wi, Whi, Wlo);
    hipLaunchKernelGGL(k_conv, dim3(BB * HH), dim3(512), 0, stream, x, Whi, Wlo, bi, bh, i2h);
    hipLaunchKernelGGL(k_lstm, dim3(BB * 4), dim3(512), 0, stream, i2h, Wh, out);
}